// Round 9
// baseline (427.495 us; speedup 1.0000x reference)
//
#include <hip/hip_runtime.h>
#include <stdint.h>

#define N_TOK 32768
#define HID   1024
#define NE    8
#define NI    2048
#define CAP   4096

typedef short s16x8 __attribute__((ext_vector_type(8)));
typedef float f32x4 __attribute__((ext_vector_type(4)));

__device__ __forceinline__ unsigned short f2bf(float f) {
    unsigned int u = __builtin_bit_cast(unsigned int, f);
    u += 0x7fffu + ((u >> 16) & 1u);
    return (unsigned short)(u >> 16);
}

__device__ __forceinline__ float bf2f(unsigned short u) {
    return __builtin_bit_cast(float, (unsigned int)u << 16);
}

__device__ __forceinline__ void gload16(const void* g, void* l) {
    __builtin_amdgcn_global_load_lds(
        (const __attribute__((address_space(1))) unsigned int*)(uintptr_t)g,
        (__attribute__((address_space(3))) unsigned int*)(unsigned int)(uintptr_t)l,
        16, 0, 0);
}

#define WAIT_LGKM0 asm volatile("s_waitcnt lgkmcnt(0)" ::: "memory")
#define WAIT_VM8   asm volatile("s_waitcnt vmcnt(8)" ::: "memory")
#define WAIT_VM0   asm volatile("s_waitcnt vmcnt(0)" ::: "memory")
#define SFENCE     __builtin_amdgcn_sched_barrier(0)
#define BARR       __builtin_amdgcn_s_barrier()

// stage a full 256x64 A- or B-tile (both 128-row halves) of K-tile TT into DST: 4 gloads
#define STG_T(DST, SRC, TT) do { \
    gload16(SRC[0][0] + (size_t)(TT) * 64 + gsl8, (DST) + wave * 1024); \
    gload16(SRC[0][1] + (size_t)(TT) * 64 + gsl8, (DST) + wave * 1024 + 512); \
    gload16(SRC[1][0] + (size_t)(TT) * 64 + gsl8, (DST) + 8192 + wave * 1024); \
    gload16(SRC[1][1] + (size_t)(TT) * 64 + gsl8, (DST) + 8192 + wave * 1024 + 512); } while (0)

// 8 ds_read_b128: A-frags for m-quadrant MH (4 mi x 2 k-slices)
#define RD_A(BASE, MH) do { \
    _Pragma("unroll") for (int m2 = 0; m2 < 4; ++m2) \
    _Pragma("unroll") for (int ks = 0; ks < 2; ++ks) \
        afr[m2*2+ks] = *(const s16x8*)((BASE) + aoff + (MH)*4096 + m2*1024 + phs[ks]); } while (0)

// 4 ds_read_b128: B-frags for n-half NH (2 ni x 2 k-slices)
#define RD_B(BF, BASE, NH) do { \
    _Pragma("unroll") for (int n2 = 0; n2 < 2; ++n2) \
    _Pragma("unroll") for (int ks = 0; ks < 2; ++ks) \
        BF[n2*2+ks] = *(const s16x8*)((BASE) + boff + (NH)*2048 + n2*1024 + phs[ks]); } while (0)

// 16 MFMA: quadrant (MH, NH)
#define MFMA_Q(MH, NH, BF) do { \
    __builtin_amdgcn_s_setprio(1); \
    _Pragma("unroll") for (int m2 = 0; m2 < 4; ++m2) \
    _Pragma("unroll") for (int n2 = 0; n2 < 2; ++n2) \
    _Pragma("unroll") for (int ks = 0; ks < 2; ++ks) \
        acc[(MH)*4+m2][(NH)*2+n2] = __builtin_amdgcn_mfma_f32_16x16x32_bf16( \
            afr[m2*2+ks], BF[n2*2+ks], acc[(MH)*4+m2][(NH)*2+n2], 0, 0, 0); \
    __builtin_amdgcn_s_setprio(0); } while (0)

// 8-phase K-loop, 2 K-tiles/iter. Whole-tile staging at ph3/4/7/8; the ONLY
// vm-waits are vmcnt(8) at ph4/ph8 end (after MFMA, before closing barrier),
// draining loads staged 4-6 phases earlier (>= HBM latency). Ledger: 16 loads
// peak in flight; tail stages clamp to T-1 (dead, keeps counts uniform).
#define KLOOP8(T) \
    for (int it = 0; it < (T) / 2; ++it) { \
        const int t0 = 2 * it; \
        const int tp2 = (t0 + 2 < (T)) ? t0 + 2 : (T) - 1; \
        const int tp3 = (t0 + 3 < (T)) ? t0 + 3 : (T) - 1; \
        /* ph1 */ \
        RD_A(Abuf0, 0); RD_B(bfr0, Bbuf0, 0); \
        SFENCE; BARR; WAIT_LGKM0; SFENCE; MFMA_Q(0, 0, bfr0); BARR; SFENCE; \
        /* ph2 */ \
        RD_B(bfr1, Bbuf0, 1); \
        SFENCE; BARR; WAIT_LGKM0; SFENCE; MFMA_Q(0, 1, bfr1); BARR; SFENCE; \
        /* ph3: stage B(t+2) -> parity-0 B buffer (B last read at ph2) */ \
        STG_T(Bbuf0, rB, tp2); \
        RD_A(Abuf0, 1); \
        SFENCE; BARR; WAIT_LGKM0; SFENCE; MFMA_Q(1, 0, bfr0); BARR; SFENCE; \
        /* ph4: stage A(t+2); vm-wait drains t+1's tiles (staged prev ph7/8) */ \
        STG_T(Abuf0, rA, tp2); \
        SFENCE; BARR; SFENCE; MFMA_Q(1, 1, bfr1); WAIT_VM8; SFENCE; BARR; SFENCE; \
        /* ph5 */ \
        RD_A(Abuf1, 0); RD_B(bfr0, Bbuf1, 0); \
        SFENCE; BARR; WAIT_LGKM0; SFENCE; MFMA_Q(0, 0, bfr0); BARR; SFENCE; \
        /* ph6 */ \
        RD_B(bfr1, Bbuf1, 1); \
        SFENCE; BARR; WAIT_LGKM0; SFENCE; MFMA_Q(0, 1, bfr1); BARR; SFENCE; \
        /* ph7: stage B(t+3) */ \
        STG_T(Bbuf1, rB, tp3); \
        RD_A(Abuf1, 1); \
        SFENCE; BARR; WAIT_LGKM0; SFENCE; MFMA_Q(1, 0, bfr0); BARR; SFENCE; \
        /* ph8: stage A(t+3); vm-wait drains t+2's tiles (staged ph3/ph4) */ \
        STG_T(Abuf1, rA, tp3); \
        SFENCE; BARR; SFENCE; MFMA_Q(1, 1, bfr1); WAIT_VM8; SFENCE; BARR; SFENCE; \
    } \
    WAIT_VM0; SFENCE; BARR; SFENCE;

// prologue: B(0),A(0),B(1),A(1) = 16 loads; drain tile0's 8, keep tile1's 8
#define KPROLOGUE \
    STG_T(Bbuf0, rB, 0); STG_T(Abuf0, rA, 0); \
    STG_T(Bbuf1, rB, 1); STG_T(Abuf1, rA, 1); \
    WAIT_VM8; SFENCE; BARR; SFENCE;

// ---------------- fp32 -> bf16 bulk convert (two tensors, one launch) ----------------
__global__ __launch_bounds__(256) void cvt2_kernel(
    const float* __restrict__ s1, unsigned short* __restrict__ d1, size_t n81,
    const float* __restrict__ s2, unsigned short* __restrict__ d2, size_t n82)
{
    size_t i = (size_t)blockIdx.x * 256 + threadIdx.x;
    size_t stride = (size_t)gridDim.x * 256;
    size_t total = n81 + n82;
    for (; i < total; i += stride) {
        const float* src; unsigned short* dst; size_t j;
        if (i < n81) { src = s1; dst = d1; j = i; }
        else         { src = s2; dst = d2; j = i - n81; }
        float4 a0 = ((const float4*)src)[2 * j];
        float4 a1 = ((const float4*)src)[2 * j + 1];
        uint4 p;
        p.x = f2bf(a0.x) | ((unsigned)f2bf(a0.y) << 16);
        p.y = f2bf(a0.z) | ((unsigned)f2bf(a0.w) << 16);
        p.z = f2bf(a1.x) | ((unsigned)f2bf(a1.y) << 16);
        p.w = f2bf(a1.z) | ((unsigned)f2bf(a1.w) << 16);
        ((uint4*)dst)[j] = p;
    }
}

// ---------------- Router: fp32 dot, top-2, softmax; fused x->bf16 ----------------
__global__ __launch_bounds__(256) void router_kernel(
    const float* __restrict__ x, const float* __restrict__ emb,
    int2* __restrict__ r_e, float2* __restrict__ r_w,
    unsigned short* __restrict__ xb)
{
    int token = blockIdx.x * 4 + (threadIdx.x >> 6);
    int lane  = threadIdx.x & 63;
    const float4* xr = (const float4*)(x + (size_t)token * HID);
    const float4* er = (const float4*)emb;

    float a[NE];
#pragma unroll
    for (int e = 0; e < NE; ++e) a[e] = 0.f;
    uint2 pk[4];
#pragma unroll
    for (int j = 0; j < 4; ++j) {
        float4 v = xr[j * 64 + lane];
        pk[j].x = f2bf(v.x) | ((unsigned)f2bf(v.y) << 16);
        pk[j].y = f2bf(v.z) | ((unsigned)f2bf(v.w) << 16);
#pragma unroll
        for (int e = 0; e < NE; ++e) {
            float4 w = er[e * 256 + j * 64 + lane];
            a[e] += v.x * w.x + v.y * w.y + v.z * w.z + v.w * w.w;
        }
    }
    uint2* xbr = (uint2*)(xb + (size_t)token * HID);
#pragma unroll
    for (int j = 0; j < 4; ++j) xbr[j * 64 + lane] = pk[j];

#pragma unroll
    for (int e = 0; e < NE; ++e) {
        for (int off = 32; off; off >>= 1) a[e] += __shfl_xor(a[e], off);
    }
    if (lane == 0) {
        float v1 = -1e30f, v2 = -1e30f; int i1 = 0, i2 = 0;
#pragma unroll
        for (int e = 0; e < NE; ++e) {
            float v = a[e];
            if (v > v1) { v2 = v1; i2 = i1; v1 = v; i1 = e; }
            else if (v > v2) { v2 = v; i2 = e; }
        }
        float ex = __expf(v2 - v1);
        r_e[token] = make_int2(i1, i2);
        r_w[token] = make_float2(1.f / (1.f + ex), ex / (1.f + ex));
    }
}

// ---------------- Capacity: count / prefix / ordered assign ----------------
__global__ __launch_bounds__(1024) void count_kernel(
    const int2* __restrict__ r_e, int* __restrict__ bc)
{
    __shared__ int cnt[NE];
    if (threadIdx.x < NE) cnt[threadIdx.x] = 0;
    __syncthreads();
    int n = blockIdx.x * 1024 + threadIdx.x;
    int2 e = r_e[n];
    atomicAdd(&cnt[e.x], 1);
    atomicAdd(&cnt[e.y], 1);
    __syncthreads();
    if (threadIdx.x < NE) bc[blockIdx.x * NE + threadIdx.x] = cnt[threadIdx.x];
}

__global__ void prefix_kernel(const int* __restrict__ bc, int* __restrict__ bb)
{
    int e = threadIdx.x;
    if (e >= NE) return;
    int run = 0;
    for (int b = 0; b < N_TOK / 1024; ++b) {
        bb[b * NE + e] = run;
        run += bc[b * NE + e];
    }
}

__global__ __launch_bounds__(1024) void assign_kernel(
    const int2* __restrict__ r_e, const float2* __restrict__ r_w,
    const int* __restrict__ bb,
    int* __restrict__ tok_list, float* __restrict__ w_list,
    int2* __restrict__ smap)
{
    __shared__ int wavecnt[16][NE];
    __shared__ int waveoff[16][NE];
    int tid = threadIdx.x, lane = tid & 63, wv = tid >> 6;
    int n = blockIdx.x * 1024 + tid;
    int2 e = r_e[n];
    float2 w = r_w[n];
    unsigned long long below = (1ull << lane) - 1ull;
    int rank0 = 0, rank1 = 0;
#pragma unroll
    for (int ex = 0; ex < NE; ++ex) {
        unsigned long long m = __ballot(e.x == ex || e.y == ex);
        if (lane == 0) wavecnt[wv][ex] = __popcll(m);
        int r = __popcll(m & below);
        if (e.x == ex) rank0 = r;
        if (e.y == ex) rank1 = r;
    }
    __syncthreads();
    if (tid < NE) {
        int run = 0;
        for (int w2 = 0; w2 < 16; ++w2) { waveoff[w2][tid] = run; run += wavecnt[w2][tid]; }
    }
    __syncthreads();
    int s0 = bb[blockIdx.x * NE + e.x] + waveoff[wv][e.x] + rank0;
    int s1 = bb[blockIdx.x * NE + e.y] + waveoff[wv][e.y] + rank1;
    int g0 = -1, g1 = -1;
    if (s0 < CAP) { tok_list[e.x * CAP + s0] = n; w_list[e.x * CAP + s0] = w.x; g0 = e.x * CAP + s0; }
    if (s1 < CAP) { tok_list[e.y * CAP + s1] = n; w_list[e.y * CAP + s1] = w.y; g1 = e.y * CAP + s1; }
    smap[n] = make_int2(g0, g1);
}

// ---------------- Combine: out[tok] = sum w[slot] * out_e[slot]  (plain stores) ------
__global__ __launch_bounds__(256) void combine_kernel(
    const unsigned short* __restrict__ out_e,
    const int2* __restrict__ smap,
    const float* __restrict__ w_list,
    float* __restrict__ out)
{
    int t  = blockIdx.x * 2 + (threadIdx.x >> 7);
    int h0 = (threadIdx.x & 127) * 8;
    int2 s = smap[t];
    float r[8];
#pragma unroll
    for (int i = 0; i < 8; ++i) r[i] = 0.f;
    if (s.x >= 0) {
        float w = w_list[s.x];
        uint4 v = *(const uint4*)(out_e + (size_t)s.x * HID + h0);
        const unsigned short* pv = (const unsigned short*)&v;
#pragma unroll
        for (int i = 0; i < 8; ++i) r[i] += w * bf2f(pv[i]);
    }
    if (s.y >= 0) {
        float w = w_list[s.y];
        uint4 v = *(const uint4*)(out_e + (size_t)s.y * HID + h0);
        const unsigned short* pv = (const unsigned short*)&v;
#pragma unroll
        for (int i = 0; i < 8; ++i) r[i] += w * bf2f(pv[i]);
    }
    float4* o = (float4*)(out + (size_t)t * HID + h0);
    o[0] = make_float4(r[0], r[1], r[2], r[3]);
    o[1] = make_float4(r[4], r[5], r[6], r[7]);
}

// ================= 256x256 8-phase GEMMs, distance-audited counted vmcnt =============

// ---------------- GEMM1: inter = relu(gather(xb) @ W1_e^T) ----------------
__global__ __launch_bounds__(512, 2) void gemm1_k(
    const unsigned short* __restrict__ xb,
    const unsigned short* __restrict__ w1b,
    const int* __restrict__ tok_list,
    unsigned short* __restrict__ inter,
    int eb)
{
    constexpr int K = HID, T = K / 64;
    __shared__ __align__(16) unsigned short smem[65536];   // 128 KB
    unsigned short* const Abuf0 = smem;
    unsigned short* const Bbuf0 = smem + 16384;
    unsigned short* const Abuf1 = smem + 32768;
    unsigned short* const Bbuf1 = smem + 49152;

    const int nblk = gridDim.x;
    const int lin  = blockIdx.x;
    const int wg   = (lin & 7) * (nblk >> 3) + (lin >> 3);  // XCD-bijective
    const int tn = wg & 7;            // NI/256
    const int tm = (wg >> 3) & 15;    // CAP/256
    const int ez = wg >> 7;
    const int e  = eb + ez;

    const int tid = threadIdx.x, lane = tid & 63, wave = tid >> 6;
    const int wr = wave >> 2, wc = wave & 3;          // 2M x 4N, per-wave 128x64
    const int gsl8 = ((lane & 7) ^ ((lane >> 3) & 7)) * 8;
    const int aoff = (wr * 128 + (lane & 15)) * 64;
    const int boff = (wc * 64 + (lane & 15)) * 64;
    const int phs[2] = { (((lane >> 4)) ^ (lane & 7)) * 8,
                         ((4 + (lane >> 4)) ^ (lane & 7)) * 8 };

    const int* tl = tok_list + e * CAP + tm * 256;
    const unsigned short* rA[2][2];
    const unsigned short* rB[2][2];
#pragma unroll
    for (int h = 0; h < 2; ++h)
#pragma unroll
        for (int j = 0; j < 2; ++j) {
            int row = h * 128 + wave * 16 + (lane >> 3) + j * 8;
            rA[h][j] = xb + (size_t)tl[row] * K;
            rB[h][j] = w1b + ((size_t)e * NI + tn * 256 + row) * K;
        }

    f32x4 acc[8][4];
#pragma unroll
    for (int i = 0; i < 8; ++i)
#pragma unroll
        for (int j = 0; j < 4; ++j) acc[i][j] = (f32x4)0.f;

    s16x8 afr[8], bfr0[4], bfr1[4];

    KPROLOGUE
#pragma unroll 1
    KLOOP8(T)

    // epilogue: relu + swizzled repack in LDS -> coalesced 16B stores
#pragma unroll
    for (int mi = 0; mi < 8; ++mi)
#pragma unroll
        for (int ni = 0; ni < 4; ++ni)
#pragma unroll
            for (int r = 0; r < 4; ++r) {
                int row = wr * 128 + mi * 16 + (lane >> 4) * 4 + r;
                int c   = wc * 64 + ni * 16 + (lane & 15);
                float v = acc[mi][ni][r];
                v = v > 0.f ? v : 0.f;
                smem[row * 256 + (((c >> 3) ^ (row & 7)) << 3) + (c & 7)] = f2bf(v);
            }
    __syncthreads();
    unsigned short* Cp = inter + ((size_t)ez * CAP + tm * 256) * NI + tn * 256;
#pragma unroll
    for (int itv = 0; itv < 16; ++itv) {
        int v = tid + itv * 512;
        int row = v >> 5, s = v & 31;
        uint4 val = *(const uint4*)&smem[row * 256 + ((s ^ (row & 7)) << 3)];
        *(uint4*)&Cp[(size_t)row * NI + s * 8] = val;
    }
}

// ---------------- GEMM2: out_e[slot] = inter @ W2_e^T  (or atomic fallback) ----------
__global__ __launch_bounds__(512, 2) void gemm2_k(
    const unsigned short* __restrict__ inter,
    const unsigned short* __restrict__ w2b,
    const int* __restrict__ tok_list,
    const float* __restrict__ w_list,
    float* __restrict__ out,
    unsigned short* __restrict__ out_e,   // non-null => combine mode
    int eb)
{
    constexpr int K = NI, T = K / 64;
    __shared__ __align__(16) unsigned short smem[65536];
    unsigned short* const Abuf0 = smem;
    unsigned short* const Bbuf0 = smem + 16384;
    unsigned short* const Abuf1 = smem + 32768;
    unsigned short* const Bbuf1 = smem + 49152;

    const int nblk = gridDim.x;
    const int lin  = blockIdx.x;
    const int wg   = (lin & 7) * (nblk >> 3) + (lin >> 3);
    const int tn = wg & 3;            // HID/256
    const int tm = (wg >> 2) & 15;    // CAP/256
    const int ez = wg >> 6;
    const int e  = eb + ez;

    const int tid = threadIdx.x, lane = tid & 63, wave = tid >> 6;
    const int wr = wave >> 2, wc = wave & 3;
    const int gsl8 = ((lane & 7) ^ ((lane >> 3) & 7)) * 8;
    const int aoff = (wr * 128 + (lane & 15)) * 64;
    const int boff = (wc * 64 + (lane & 15)) * 64;
    const int phs[2] = { (((lane >> 4)) ^ (lane & 7)) * 8,
                         ((4 + (lane >> 4)) ^ (lane & 7)) * 8 };

    const unsigned short* rA[2][2];
    const unsigned short* rB[2][2];
#pragma unroll
    for (int h = 0; h < 2; ++h)
#pragma unroll
        for (int j = 0; j < 2; ++j) {
            int row = h * 128 + wave * 16 + (lane >> 3) + j * 8;
            rA[h][j] = inter + ((size_t)ez * CAP + tm * 256 + row) * (size_t)K;
            rB[h][j] = w2b + ((size_t)e * HID + tn * 256 + row) * (size_t)K;
        }

    f32x4 acc[8][4];
#pragma unroll
    for (int i = 0; i < 8; ++i)
#pragma unroll
        for (int j = 0; j < 4; ++j) acc[i][j] = (f32x4)0.f;

    s16x8 afr[8], bfr0[4], bfr1[4];

    KPROLOGUE
#pragma unroll 1
    KLOOP8(T)

    if (out_e) {
        // combine mode: unweighted bf16 stores via swizzled LDS repack
#pragma unroll
        for (int mi = 0; mi < 8; ++mi)
#pragma unroll
            for (int ni = 0; ni < 4; ++ni)
#pragma unroll
                for (int r = 0; r < 4; ++r) {
                    int row = wr * 128 + mi * 16 + (lane >> 4) * 4 + r;
                    int c   = wc * 64 + ni * 16 + (lane & 15);
                    smem[row * 256 + (((c >> 3) ^ (row & 7)) << 3) + (c & 7)] = f2bf(acc[mi][ni][r]);
                }
        __syncthreads();
        unsigned short* Cp = out_e + ((size_t)e * CAP + tm * 256) * HID + tn * 256;
#pragma unroll
        for (int itv = 0; itv < 16; ++itv) {
            int v = tid + itv * 512;
            int row = v >> 5, s = v & 31;
            uint4 val = *(const uint4*)&smem[row * 256 + ((s ^ (row & 7)) << 3)];
            *(uint4*)&Cp[(size_t)row * HID + s * 8] = val;
        }
    } else {
        const int* tl   = tok_list + e * CAP + tm * 256;
        const float* wl = w_list  + e * CAP + tm * 256;
#pragma unroll
        for (int mi = 0; mi < 8; ++mi)
#pragma unroll
            for (int r = 0; r < 4; ++r) {
                int rrow = wr * 128 + mi * 16 + (lane >> 4) * 4 + r;
                int tok  = tl[rrow];
                float w  = wl[rrow];
                float* orow = out + (size_t)tok * HID + tn * 256 + wc * 64;
#pragma unroll
                for (int ni = 0; ni < 4; ++ni)
                    atomicAdd(&orow[ni * 16 + (lane & 15)], acc[mi][ni][r] * w);
            }
    }
}

extern "C" void kernel_launch(void* const* d_in, const int* in_sizes, int n_in,
                              void* d_out, int out_size, void* d_ws, size_t ws_size,
                              hipStream_t stream)
{
    const float* x   = (const float*)d_in[0];
    const float* emb = (const float*)d_in[1];
    const float* W1  = (const float*)d_in[2];
    const float* W2  = (const float*)d_in[3];
    float* out = (float*)d_out;

    size_t off = 0;
    auto alloc = [&](size_t bytes) -> void* {
        void* p = (char*)d_ws + off;
        off += (bytes + 255) & ~(size_t)255;
        return p;
    };
    const size_t sz_w  = (size_t)NE * NI * HID * 2;
    const size_t sz_xb = (size_t)N_TOK * HID * 2;

    int*   tok_list = (int*)alloc((size_t)NE * CAP * 4);
    float* w_list   = (float*)alloc((size_t)NE * CAP * 4);
    int2*  smap     = (int2*)alloc((size_t)N_TOK * 8);
    unsigned short* w1b = (unsigned short*)alloc(sz_w);
    unsigned short* w2b = (unsigned short*)alloc(sz_w);
    unsigned short* xb  = (unsigned short*)alloc(sz_xb);

    unsigned short* inter = (unsigned short*)((char*)d_ws + off);
    size_t avail = ws_size > off ? ws_size - off : 0;
    const size_t per_e = (size_t)CAP * NI * 2;
    int G = (avail >= 8 * per_e) ? 8 : (avail >= 4 * per_e) ? 4
          : (avail >= 2 * per_e) ? 2 : 1;
    const bool combine = (G == 8);
    unsigned short* out_e = combine ? xb : nullptr;   // aliases xb (dead after gemm1)

    int2*   r_e = (int2*)inter;
    float2* r_w = (float2*)((char*)inter + (size_t)N_TOK * 8);
    int*    bc  = (int*)((char*)inter + (size_t)N_TOK * 16);
    int*    bb  = bc + (N_TOK / 1024) * NE;

    if (!combine)
        hipMemsetAsync(d_out, 0, (size_t)N_TOK * HID * 4, stream);
    hipMemsetAsync(tok_list, 0, (size_t)NE * CAP * 4, stream);
    hipMemsetAsync(w_list, 0, (size_t)NE * CAP * 4, stream);

    cvt2_kernel<<<2048, 256, 0, stream>>>(W1, w1b, (size_t)NE * NI * HID / 8,
                                          W2, w2b, (size_t)NE * HID * NI / 8);
    router_kernel<<<N_TOK / 4, 256, 0, stream>>>(x, emb, r_e, r_w, xb);
    count_kernel<<<N_TOK / 1024, 1024, 0, stream>>>(r_e, bc);
    prefix_kernel<<<1, 64, 0, stream>>>(bc, bb);
    assign_kernel<<<N_TOK / 1024, 1024, 0, stream>>>(r_e, r_w, bb, tok_list, w_list, smap);

    for (int eb = 0; eb < NE; eb += G) {
        gemm1_k<<<dim3(8 * 16 * G), 512, 0, stream>>>(xb, w1b, tok_list, inter, eb);
        gemm2_k<<<dim3(4 * 16 * G), 512, 0, stream>>>(inter, w2b, tok_list, w_list, out, out_e, eb);
    }
    if (combine)
        combine_kernel<<<N_TOK / 2, 256, 0, stream>>>(out_e, smap, w_list, out);
}

// Round 10
// 420.701 us; speedup vs baseline: 1.0161x; 1.0161x over previous
//
#include <hip/hip_runtime.h>
#include <stdint.h>

#define N_TOK 32768
#define HID   1024
#define NE    8
#define NI    2048
#define CAP   4096

typedef short s16x8 __attribute__((ext_vector_type(8)));
typedef float f32x4 __attribute__((ext_vector_type(4)));

__device__ __forceinline__ unsigned short f2bf(float f) {
    unsigned int u = __builtin_bit_cast(unsigned int, f);
    u += 0x7fffu + ((u >> 16) & 1u);
    return (unsigned short)(u >> 16);
}

__device__ __forceinline__ float bf2f(unsigned short u) {
    return __builtin_bit_cast(float, (unsigned int)u << 16);
}

__device__ __forceinline__ void gload16(const void* g, void* l) {
    __builtin_amdgcn_global_load_lds(
        (const __attribute__((address_space(1))) unsigned int*)(uintptr_t)g,
        (__attribute__((address_space(3))) unsigned int*)(unsigned int)(uintptr_t)l,
        16, 0, 0);
}

// ---------------- fp32 -> bf16 bulk convert (two tensors, one launch) ----------------
__global__ __launch_bounds__(256) void cvt2_kernel(
    const float* __restrict__ s1, unsigned short* __restrict__ d1, size_t n81,
    const float* __restrict__ s2, unsigned short* __restrict__ d2, size_t n82)
{
    size_t i = (size_t)blockIdx.x * 256 + threadIdx.x;
    size_t stride = (size_t)gridDim.x * 256;
    size_t total = n81 + n82;
    for (; i < total; i += stride) {
        const float* src; unsigned short* dst; size_t j;
        if (i < n81) { src = s1; dst = d1; j = i; }
        else         { src = s2; dst = d2; j = i - n81; }
        float4 a0 = ((const float4*)src)[2 * j];
        float4 a1 = ((const float4*)src)[2 * j + 1];
        uint4 p;
        p.x = f2bf(a0.x) | ((unsigned)f2bf(a0.y) << 16);
        p.y = f2bf(a0.z) | ((unsigned)f2bf(a0.w) << 16);
        p.z = f2bf(a1.x) | ((unsigned)f2bf(a1.y) << 16);
        p.w = f2bf(a1.z) | ((unsigned)f2bf(a1.w) << 16);
        ((uint4*)dst)[j] = p;
    }
}

// ---------------- Router: fp32 dot, top-2, softmax; fused x->bf16 ----------------
__global__ __launch_bounds__(256) void router_kernel(
    const float* __restrict__ x, const float* __restrict__ emb,
    int2* __restrict__ r_e, float2* __restrict__ r_w,
    unsigned short* __restrict__ xb)
{
    int token = blockIdx.x * 4 + (threadIdx.x >> 6);
    int lane  = threadIdx.x & 63;
    const float4* xr = (const float4*)(x + (size_t)token * HID);
    const float4* er = (const float4*)emb;

    float a[NE];
#pragma unroll
    for (int e = 0; e < NE; ++e) a[e] = 0.f;
    uint2 pk[4];
#pragma unroll
    for (int j = 0; j < 4; ++j) {
        float4 v = xr[j * 64 + lane];
        pk[j].x = f2bf(v.x) | ((unsigned)f2bf(v.y) << 16);
        pk[j].y = f2bf(v.z) | ((unsigned)f2bf(v.w) << 16);
#pragma unroll
        for (int e = 0; e < NE; ++e) {
            float4 w = er[e * 256 + j * 64 + lane];
            a[e] += v.x * w.x + v.y * w.y + v.z * w.z + v.w * w.w;
        }
    }
    uint2* xbr = (uint2*)(xb + (size_t)token * HID);
#pragma unroll
    for (int j = 0; j < 4; ++j) xbr[j * 64 + lane] = pk[j];

#pragma unroll
    for (int e = 0; e < NE; ++e) {
        for (int off = 32; off; off >>= 1) a[e] += __shfl_xor(a[e], off);
    }
    if (lane == 0) {
        float v1 = -1e30f, v2 = -1e30f; int i1 = 0, i2 = 0;
#pragma unroll
        for (int e = 0; e < NE; ++e) {
            float v = a[e];
            if (v > v1) { v2 = v1; i2 = i1; v1 = v; i1 = e; }
            else if (v > v2) { v2 = v; i2 = e; }
        }
        float ex = __expf(v2 - v1);
        r_e[token] = make_int2(i1, i2);
        r_w[token] = make_float2(1.f / (1.f + ex), ex / (1.f + ex));
    }
}

// ---------------- Capacity: count / prefix / ordered assign ----------------
__global__ __launch_bounds__(1024) void count_kernel(
    const int2* __restrict__ r_e, int* __restrict__ bc)
{
    __shared__ int cnt[NE];
    if (threadIdx.x < NE) cnt[threadIdx.x] = 0;
    __syncthreads();
    int n = blockIdx.x * 1024 + threadIdx.x;
    int2 e = r_e[n];
    atomicAdd(&cnt[e.x], 1);
    atomicAdd(&cnt[e.y], 1);
    __syncthreads();
    if (threadIdx.x < NE) bc[blockIdx.x * NE + threadIdx.x] = cnt[threadIdx.x];
}

__global__ void prefix_kernel(const int* __restrict__ bc, int* __restrict__ bb)
{
    int e = threadIdx.x;
    if (e >= NE) return;
    int run = 0;
    for (int b = 0; b < N_TOK / 1024; ++b) {
        bb[b * NE + e] = run;
        run += bc[b * NE + e];
    }
}

__global__ __launch_bounds__(1024) void assign_kernel(
    const int2* __restrict__ r_e, const float2* __restrict__ r_w,
    const int* __restrict__ bb,
    int* __restrict__ tok_list, float* __restrict__ w_list,
    int2* __restrict__ smap)
{
    __shared__ int wavecnt[16][NE];
    __shared__ int waveoff[16][NE];
    int tid = threadIdx.x, lane = tid & 63, wv = tid >> 6;
    int n = blockIdx.x * 1024 + tid;
    int2 e = r_e[n];
    float2 w = r_w[n];
    unsigned long long below = (1ull << lane) - 1ull;
    int rank0 = 0, rank1 = 0;
#pragma unroll
    for (int ex = 0; ex < NE; ++ex) {
        unsigned long long m = __ballot(e.x == ex || e.y == ex);
        if (lane == 0) wavecnt[wv][ex] = __popcll(m);
        int r = __popcll(m & below);
        if (e.x == ex) rank0 = r;
        if (e.y == ex) rank1 = r;
    }
    __syncthreads();
    if (tid < NE) {
        int run = 0;
        for (int w2 = 0; w2 < 16; ++w2) { waveoff[w2][tid] = run; run += wavecnt[w2][tid]; }
    }
    __syncthreads();
    int s0 = bb[blockIdx.x * NE + e.x] + waveoff[wv][e.x] + rank0;
    int s1 = bb[blockIdx.x * NE + e.y] + waveoff[wv][e.y] + rank1;
    int g0 = -1, g1 = -1;
    if (s0 < CAP) { tok_list[e.x * CAP + s0] = n; w_list[e.x * CAP + s0] = w.x; g0 = e.x * CAP + s0; }
    if (s1 < CAP) { tok_list[e.y * CAP + s1] = n; w_list[e.y * CAP + s1] = w.y; g1 = e.y * CAP + s1; }
    smap[n] = make_int2(g0, g1);
}

// ---------------- Combine: out[tok] = sum w[slot] * out_e[slot]  (plain stores) ------
__global__ __launch_bounds__(256) void combine_kernel(
    const unsigned short* __restrict__ out_e,
    const int2* __restrict__ smap,
    const float* __restrict__ w_list,
    float* __restrict__ out)
{
    int t  = blockIdx.x * 2 + (threadIdx.x >> 7);
    int h0 = (threadIdx.x & 127) * 8;
    int2 s = smap[t];
    float r[8];
#pragma unroll
    for (int i = 0; i < 8; ++i) r[i] = 0.f;
    if (s.x >= 0) {
        float w = w_list[s.x];
        uint4 v = *(const uint4*)(out_e + (size_t)s.x * HID + h0);
        const unsigned short* pv = (const unsigned short*)&v;
#pragma unroll
        for (int i = 0; i < 8; ++i) r[i] += w * bf2f(pv[i]);
    }
    if (s.y >= 0) {
        float w = w_list[s.y];
        uint4 v = *(const uint4*)(out_e + (size_t)s.y * HID + h0);
        const unsigned short* pv = (const unsigned short*)&v;
#pragma unroll
        for (int i = 0; i < 8; ++i) r[i] += w * bf2f(pv[i]);
    }
    float4* o = (float4*)(out + (size_t)t * HID + h0);
    o[0] = make_float4(r[0], r[1], r[2], r[3]);
    o[1] = make_float4(r[4], r[5], r[6], r[7]);
}

// ================= m97-structure GEMMs: 128x128 tile, BK=64, 4 waves, =================
// ================= single-buffered 32 KB LDS, global_load_lds w16, 2 syncs/iter ======

// ---------------- GEMM1: inter = relu(gather(xb) @ W1_e^T) ----------------
__global__ __launch_bounds__(256, 4) void gemm1_k(
    const unsigned short* __restrict__ xb,
    const unsigned short* __restrict__ w1b,
    const int* __restrict__ tok_list,
    unsigned short* __restrict__ inter,
    int eb)
{
    constexpr int K = HID, T = K / 64;
    __shared__ __align__(16) unsigned short smem[16384];   // 32 KB
    unsigned short* As = smem;
    unsigned short* Bs = smem + 8192;

    const int nblk = gridDim.x;
    const int lin  = blockIdx.x;
    const int wg   = (lin & 7) * (nblk >> 3) + (lin >> 3);  // XCD-bijective
    const int tn = wg & 15;           // NI/128
    const int tm = (wg >> 4) & 31;    // CAP/128
    const int ez = wg >> 9;
    const int e  = eb + ez;

    const int tid = threadIdx.x, lane = tid & 63, wave = tid >> 6;
    const int wr = wave >> 1, wc = wave & 1;
    const int gsl8 = ((lane & 7) ^ ((lane >> 3) & 7)) * 8;
    const int abase = (wr * 64 + (lane & 15)) * 64;
    const int bbase = (wc * 64 + (lane & 15)) * 64;
    const int phs[2] = { (((lane >> 4)) ^ (lane & 7)) * 8,
                         ((4 + (lane >> 4)) ^ (lane & 7)) * 8 };

    const int* tl = tok_list + e * CAP + tm * 128;
    const unsigned short* srcA[4];
    const unsigned short* srcB[4];
#pragma unroll
    for (int c = 0; c < 4; ++c) {
        int row = c * 32 + wave * 8 + (lane >> 3);
        srcA[c] = xb + (size_t)tl[row] * K + gsl8;
        srcB[c] = w1b + ((size_t)e * NI + tn * 128 + row) * K + gsl8;
    }

    f32x4 acc[4][4];
#pragma unroll
    for (int i = 0; i < 4; ++i)
#pragma unroll
        for (int j = 0; j < 4; ++j) acc[i][j] = (f32x4)0.f;

    for (int t = 0; t < T; ++t) {
#pragma unroll
        for (int c = 0; c < 4; ++c) {
            unsigned short* d = smem + (c * 32 + wave * 8) * 64;
            gload16(srcA[c] + t * 64, d);
            gload16(srcB[c] + t * 64, d + 8192);
        }
        __syncthreads();
#pragma unroll
        for (int ks = 0; ks < 2; ++ks) {
            s16x8 af[4], bf[4];
#pragma unroll
            for (int mi = 0; mi < 4; ++mi)
                af[mi] = *(const s16x8*)(As + abase + mi * 1024 + phs[ks]);
#pragma unroll
            for (int ni = 0; ni < 4; ++ni)
                bf[ni] = *(const s16x8*)(Bs + bbase + ni * 1024 + phs[ks]);
#pragma unroll
            for (int mi = 0; mi < 4; ++mi)
#pragma unroll
                for (int ni = 0; ni < 4; ++ni)
                    acc[mi][ni] = __builtin_amdgcn_mfma_f32_16x16x32_bf16(
                        af[mi], bf[ni], acc[mi][ni], 0, 0, 0);
        }
        __syncthreads();
    }

    // epilogue: relu -> swizzled LDS repack -> coalesced 16B stores
#pragma unroll
    for (int mi = 0; mi < 4; ++mi)
#pragma unroll
        for (int ni = 0; ni < 4; ++ni)
#pragma unroll
            for (int r = 0; r < 4; ++r) {
                int row = wr * 64 + mi * 16 + (lane >> 4) * 4 + r;
                int c   = wc * 64 + ni * 16 + (lane & 15);
                float v = acc[mi][ni][r];
                v = v > 0.f ? v : 0.f;
                smem[row * 128 + (((c >> 3) ^ (row & 7)) << 3) + (c & 7)] = f2bf(v);
            }
    __syncthreads();
    unsigned short* Cp = inter + ((size_t)ez * CAP + tm * 128) * NI + tn * 128;
#pragma unroll
    for (int it = 0; it < 8; ++it) {
        int v = tid + it * 256;
        int row = v >> 4, s = v & 15;
        uint4 val = *(const uint4*)&smem[row * 128 + ((s ^ (row & 7)) << 3)];
        *(uint4*)&Cp[(size_t)row * NI + s * 8] = val;
    }
}

// ---------------- GEMM2: out_e[slot] = inter @ W2_e^T  (or atomic fallback) ----------
__global__ __launch_bounds__(256, 4) void gemm2_k(
    const unsigned short* __restrict__ inter,
    const unsigned short* __restrict__ w2b,
    const int* __restrict__ tok_list,
    const float* __restrict__ w_list,
    float* __restrict__ out,
    unsigned short* __restrict__ out_e,   // non-null => combine mode
    int eb)
{
    constexpr int K = NI, T = K / 64;
    __shared__ __align__(16) unsigned short smem[16384];
    unsigned short* As = smem;
    unsigned short* Bs = smem + 8192;

    const int nblk = gridDim.x;
    const int lin  = blockIdx.x;
    const int wg   = (lin & 7) * (nblk >> 3) + (lin >> 3);
    const int tn = wg & 7;            // HID/128
    const int tm = (wg >> 3) & 31;    // CAP/128
    const int ez = wg >> 8;
    const int e  = eb + ez;

    const int tid = threadIdx.x, lane = tid & 63, wave = tid >> 6;
    const int wr = wave >> 1, wc = wave & 1;
    const int gsl8 = ((lane & 7) ^ ((lane >> 3) & 7)) * 8;
    const int abase = (wr * 64 + (lane & 15)) * 64;
    const int bbase = (wc * 64 + (lane & 15)) * 64;
    const int phs[2] = { (((lane >> 4)) ^ (lane & 7)) * 8,
                         ((4 + (lane >> 4)) ^ (lane & 7)) * 8 };

    const unsigned short* srcA[4];
    const unsigned short* srcB[4];
#pragma unroll
    for (int c = 0; c < 4; ++c) {
        int row = c * 32 + wave * 8 + (lane >> 3);
        srcA[c] = inter + ((size_t)ez * CAP + tm * 128 + row) * (size_t)K + gsl8;
        srcB[c] = w2b + ((size_t)e * HID + tn * 128 + row) * (size_t)K + gsl8;
    }

    f32x4 acc[4][4];
#pragma unroll
    for (int i = 0; i < 4; ++i)
#pragma unroll
        for (int j = 0; j < 4; ++j) acc[i][j] = (f32x4)0.f;

    for (int t = 0; t < T; ++t) {
#pragma unroll
        for (int c = 0; c < 4; ++c) {
            unsigned short* d = smem + (c * 32 + wave * 8) * 64;
            gload16(srcA[c] + t * 64, d);
            gload16(srcB[c] + t * 64, d + 8192);
        }
        __syncthreads();
#pragma unroll
        for (int ks = 0; ks < 2; ++ks) {
            s16x8 af[4], bf[4];
#pragma unroll
            for (int mi = 0; mi < 4; ++mi)
                af[mi] = *(const s16x8*)(As + abase + mi * 1024 + phs[ks]);
#pragma unroll
            for (int ni = 0; ni < 4; ++ni)
                bf[ni] = *(const s16x8*)(Bs + bbase + ni * 1024 + phs[ks]);
#pragma unroll
            for (int mi = 0; mi < 4; ++mi)
#pragma unroll
                for (int ni = 0; ni < 4; ++ni)
                    acc[mi][ni] = __builtin_amdgcn_mfma_f32_16x16x32_bf16(
                        af[mi], bf[ni], acc[mi][ni], 0, 0, 0);
        }
        __syncthreads();
    }

    if (out_e) {
        // combine mode: unweighted bf16 stores via swizzled LDS repack
#pragma unroll
        for (int mi = 0; mi < 4; ++mi)
#pragma unroll
            for (int ni = 0; ni < 4; ++ni)
#pragma unroll
                for (int r = 0; r < 4; ++r) {
                    int row = wr * 64 + mi * 16 + (lane >> 4) * 4 + r;
                    int c   = wc * 64 + ni * 16 + (lane & 15);
                    smem[row * 128 + (((c >> 3) ^ (row & 7)) << 3) + (c & 7)] = f2bf(acc[mi][ni][r]);
                }
        __syncthreads();
        unsigned short* Cp = out_e + ((size_t)e * CAP + tm * 128) * HID + tn * 128;
#pragma unroll
        for (int it = 0; it < 8; ++it) {
            int v = tid + it * 256;
            int row = v >> 4, s = v & 15;
            uint4 val = *(const uint4*)&smem[row * 128 + ((s ^ (row & 7)) << 3)];
            *(uint4*)&Cp[(size_t)row * HID + s * 8] = val;
        }
    } else {
        const int* tl   = tok_list + e * CAP + tm * 128;
        const float* wl = w_list  + e * CAP + tm * 128;
#pragma unroll
        for (int mi = 0; mi < 4; ++mi)
#pragma unroll
            for (int r = 0; r < 4; ++r) {
                int rrow = wr * 64 + mi * 16 + (lane >> 4) * 4 + r;
                int tok  = tl[rrow];
                float w  = wl[rrow];
                float* orow = out + (size_t)tok * HID + tn * 128 + wc * 64;
#pragma unroll
                for (int ni = 0; ni < 4; ++ni)
                    atomicAdd(&orow[ni * 16 + (lane & 15)], acc[mi][ni][r] * w);
            }
    }
}

extern "C" void kernel_launch(void* const* d_in, const int* in_sizes, int n_in,
                              void* d_out, int out_size, void* d_ws, size_t ws_size,
                              hipStream_t stream)
{
    const float* x   = (const float*)d_in[0];
    const float* emb = (const float*)d_in[1];
    const float* W1  = (const float*)d_in[2];
    const float* W2  = (const float*)d_in[3];
    float* out = (float*)d_out;

    size_t off = 0;
    auto alloc = [&](size_t bytes) -> void* {
        void* p = (char*)d_ws + off;
        off += (bytes + 255) & ~(size_t)255;
        return p;
    };
    const size_t sz_w  = (size_t)NE * NI * HID * 2;
    const size_t sz_xb = (size_t)N_TOK * HID * 2;

    int*   tok_list = (int*)alloc((size_t)NE * CAP * 4);
    float* w_list   = (float*)alloc((size_t)NE * CAP * 4);
    int2*  smap     = (int2*)alloc((size_t)N_TOK * 8);
    unsigned short* w1b = (unsigned short*)alloc(sz_w);
    unsigned short* w2b = (unsigned short*)alloc(sz_w);
    unsigned short* xb  = (unsigned short*)alloc(sz_xb);

    unsigned short* inter = (unsigned short*)((char*)d_ws + off);
    size_t avail = ws_size > off ? ws_size - off : 0;
    const size_t per_e = (size_t)CAP * NI * 2;
    int G = (avail >= 8 * per_e) ? 8 : (avail >= 4 * per_e) ? 4
          : (avail >= 2 * per_e) ? 2 : 1;
    // combine mode: out_e (NE*CAP*HID bf16 = 67.1 MB) aliases xb, which is dead
    // after the (single, G=8) gemm1 launch completes.
    const bool combine = (G == 8);
    unsigned short* out_e = combine ? xb : nullptr;

    int2*   r_e = (int2*)inter;
    float2* r_w = (float2*)((char*)inter + (size_t)N_TOK * 8);
    int*    bc  = (int*)((char*)inter + (size_t)N_TOK * 16);
    int*    bb  = bc + (N_TOK / 1024) * NE;

    if (!combine)
        hipMemsetAsync(d_out, 0, (size_t)N_TOK * HID * 4, stream);
    hipMemsetAsync(tok_list, 0, (size_t)NE * CAP * 4, stream);
    hipMemsetAsync(w_list, 0, (size_t)NE * CAP * 4, stream);

    cvt2_kernel<<<2048, 256, 0, stream>>>(W1, w1b, (size_t)NE * NI * HID / 8,
                                          W2, w2b, (size_t)NE * HID * NI / 8);
    router_kernel<<<N_TOK / 4, 256, 0, stream>>>(x, emb, r_e, r_w, xb);
    count_kernel<<<N_TOK / 1024, 1024, 0, stream>>>(r_e, bc);
    prefix_kernel<<<1, 64, 0, stream>>>(bc, bb);
    assign_kernel<<<N_TOK / 1024, 1024, 0, stream>>>(r_e, r_w, bb, tok_list, w_list, smap);

    for (int eb = 0; eb < NE; eb += G) {
        gemm1_k<<<dim3(16 * 32 * G), 256, 0, stream>>>(xb, w1b, tok_list, inter, eb);
        gemm2_k<<<dim3(8 * 32 * G), 256, 0, stream>>>(inter, w2b, tok_list, w_list, out, out_e, eb);
    }
    if (combine)
        combine_kernel<<<N_TOK / 2, 256, 0, stream>>>(out_e, smap, w_list, out);
}

// Round 11
// 420.394 us; speedup vs baseline: 1.0169x; 1.0007x over previous
//
#include <hip/hip_runtime.h>
#include <stdint.h>

#define N_TOK 32768
#define HID   1024
#define NE    8
#define NI    2048
#define CAP   4096

typedef short s16x8 __attribute__((ext_vector_type(8)));
typedef float f32x4 __attribute__((ext_vector_type(4)));

__device__ __forceinline__ unsigned short f2bf(float f) {
    unsigned int u = __builtin_bit_cast(unsigned int, f);
    u += 0x7fffu + ((u >> 16) & 1u);
    return (unsigned short)(u >> 16);
}

__device__ __forceinline__ float bf2f(unsigned short u) {
    return __builtin_bit_cast(float, (unsigned int)u << 16);
}

__device__ __forceinline__ void gload16(const void* g, void* l) {
    __builtin_amdgcn_global_load_lds(
        (const __attribute__((address_space(1))) unsigned int*)(uintptr_t)g,
        (__attribute__((address_space(3))) unsigned int*)(unsigned int)(uintptr_t)l,
        16, 0, 0);
}

__device__ __forceinline__ uint4 packchunk(const float* src, size_t g) {
    float4 a0 = ((const float4*)src)[2 * g];
    float4 a1 = ((const float4*)src)[2 * g + 1];
    uint4 p;
    p.x = f2bf(a0.x) | ((unsigned)f2bf(a0.y) << 16);
    p.y = f2bf(a0.z) | ((unsigned)f2bf(a0.w) << 16);
    p.z = f2bf(a1.x) | ((unsigned)f2bf(a1.y) << 16);
    p.w = f2bf(a1.z) | ((unsigned)f2bf(a1.w) << 16);
    return p;
}

// ---------------- fp32 -> bf16 bulk convert (fallback tiers only) ----------------
__global__ __launch_bounds__(256) void cvt2_kernel(
    const float* __restrict__ s1, unsigned short* __restrict__ d1, size_t n81,
    const float* __restrict__ s2, unsigned short* __restrict__ d2, size_t n82)
{
    size_t i = (size_t)blockIdx.x * 256 + threadIdx.x;
    size_t stride = (size_t)gridDim.x * 256;
    size_t total = n81 + n82;
    for (; i < total; i += stride) {
        const float* src; unsigned short* dst; size_t j;
        if (i < n81) { src = s1; dst = d1; j = i; }
        else         { src = s2; dst = d2; j = i - n81; }
        ((uint4*)dst)[j] = packchunk(src, j);
    }
}

// ---------------- Router: fp32 dot, top-2, softmax; fused x->bf16 + W1->bf16 ---------
__global__ __launch_bounds__(256) void router_kernel(
    const float* __restrict__ x, const float* __restrict__ emb,
    int2* __restrict__ r_e, float2* __restrict__ r_w,
    unsigned short* __restrict__ xb,
    const float* __restrict__ w1f, unsigned short* __restrict__ w1b)
{
    // fused W1 conversion: grid has exactly NE*NI*HID/8 = 2,097,152 threads;
    // one 8-element chunk per thread, fully coalesced.
    if (w1f) {
        size_t g = (size_t)blockIdx.x * 256 + threadIdx.x;
        ((uint4*)w1b)[g] = packchunk(w1f, g);
    }

    int token = blockIdx.x * 4 + (threadIdx.x >> 6);
    int lane  = threadIdx.x & 63;
    const float4* xr = (const float4*)(x + (size_t)token * HID);
    const float4* er = (const float4*)emb;

    float a[NE];
#pragma unroll
    for (int e = 0; e < NE; ++e) a[e] = 0.f;
    uint2 pk[4];
#pragma unroll
    for (int j = 0; j < 4; ++j) {
        float4 v = xr[j * 64 + lane];
        pk[j].x = f2bf(v.x) | ((unsigned)f2bf(v.y) << 16);
        pk[j].y = f2bf(v.z) | ((unsigned)f2bf(v.w) << 16);
#pragma unroll
        for (int e = 0; e < NE; ++e) {
            float4 w = er[e * 256 + j * 64 + lane];
            a[e] += v.x * w.x + v.y * w.y + v.z * w.z + v.w * w.w;
        }
    }
    uint2* xbr = (uint2*)(xb + (size_t)token * HID);
#pragma unroll
    for (int j = 0; j < 4; ++j) xbr[j * 64 + lane] = pk[j];

#pragma unroll
    for (int e = 0; e < NE; ++e) {
        for (int off = 32; off; off >>= 1) a[e] += __shfl_xor(a[e], off);
    }
    if (lane == 0) {
        float v1 = -1e30f, v2 = -1e30f; int i1 = 0, i2 = 0;
#pragma unroll
        for (int e = 0; e < NE; ++e) {
            float v = a[e];
            if (v > v1) { v2 = v1; i2 = i1; v1 = v; i1 = e; }
            else if (v > v2) { v2 = v; i2 = e; }
        }
        float ex = __expf(v2 - v1);
        r_e[token] = make_int2(i1, i2);
        r_w[token] = make_float2(1.f / (1.f + ex), ex / (1.f + ex));
    }
}

// ---------------- Capacity: count / prefix / ordered assign ----------------
__global__ __launch_bounds__(1024) void count_kernel(
    const int2* __restrict__ r_e, int* __restrict__ bc)
{
    __shared__ int cnt[NE];
    if (threadIdx.x < NE) cnt[threadIdx.x] = 0;
    __syncthreads();
    int n = blockIdx.x * 1024 + threadIdx.x;
    int2 e = r_e[n];
    atomicAdd(&cnt[e.x], 1);
    atomicAdd(&cnt[e.y], 1);
    __syncthreads();
    if (threadIdx.x < NE) bc[blockIdx.x * NE + threadIdx.x] = cnt[threadIdx.x];
}

__global__ void prefix_kernel(const int* __restrict__ bc, int* __restrict__ bb)
{
    int e = threadIdx.x;
    if (e >= NE) return;
    int run = 0;
    for (int b = 0; b < N_TOK / 1024; ++b) {
        bb[b * NE + e] = run;
        run += bc[b * NE + e];
    }
}

__global__ __launch_bounds__(1024) void assign_kernel(
    const int2* __restrict__ r_e, const float2* __restrict__ r_w,
    const int* __restrict__ bb,
    int* __restrict__ tok_list, float* __restrict__ w_list,
    int2* __restrict__ smap)
{
    __shared__ int wavecnt[16][NE];
    __shared__ int waveoff[16][NE];
    int tid = threadIdx.x, lane = tid & 63, wv = tid >> 6;
    int n = blockIdx.x * 1024 + tid;
    int2 e = r_e[n];
    float2 w = r_w[n];
    unsigned long long below = (1ull << lane) - 1ull;
    int rank0 = 0, rank1 = 0;
#pragma unroll
    for (int ex = 0; ex < NE; ++ex) {
        unsigned long long m = __ballot(e.x == ex || e.y == ex);
        if (lane == 0) wavecnt[wv][ex] = __popcll(m);
        int r = __popcll(m & below);
        if (e.x == ex) rank0 = r;
        if (e.y == ex) rank1 = r;
    }
    __syncthreads();
    if (tid < NE) {
        int run = 0;
        for (int w2 = 0; w2 < 16; ++w2) { waveoff[w2][tid] = run; run += wavecnt[w2][tid]; }
    }
    __syncthreads();
    int s0 = bb[blockIdx.x * NE + e.x] + waveoff[wv][e.x] + rank0;
    int s1 = bb[blockIdx.x * NE + e.y] + waveoff[wv][e.y] + rank1;
    int g0 = -1, g1 = -1;
    if (s0 < CAP) { tok_list[e.x * CAP + s0] = n; w_list[e.x * CAP + s0] = w.x; g0 = e.x * CAP + s0; }
    if (s1 < CAP) { tok_list[e.y * CAP + s1] = n; w_list[e.y * CAP + s1] = w.y; g1 = e.y * CAP + s1; }
    smap[n] = make_int2(g0, g1);
}

// ---------------- Combine: out[tok] = sum w[slot] * out_e[slot]  (plain stores) ------
__global__ __launch_bounds__(256) void combine_kernel(
    const unsigned short* __restrict__ out_e,
    const int2* __restrict__ smap,
    const float* __restrict__ w_list,
    float* __restrict__ out)
{
    int t  = blockIdx.x * 2 + (threadIdx.x >> 7);
    int h0 = (threadIdx.x & 127) * 8;
    int2 s = smap[t];
    float r[8];
#pragma unroll
    for (int i = 0; i < 8; ++i) r[i] = 0.f;
    if (s.x >= 0) {
        float w = w_list[s.x];
        uint4 v = *(const uint4*)(out_e + (size_t)s.x * HID + h0);
        const unsigned short* pv = (const unsigned short*)&v;
#pragma unroll
        for (int i = 0; i < 8; ++i) r[i] += w * bf2f(pv[i]);
    }
    if (s.y >= 0) {
        float w = w_list[s.y];
        uint4 v = *(const uint4*)(out_e + (size_t)s.y * HID + h0);
        const unsigned short* pv = (const unsigned short*)&v;
#pragma unroll
        for (int i = 0; i < 8; ++i) r[i] += w * bf2f(pv[i]);
    }
    float4* o = (float4*)(out + (size_t)t * HID + h0);
    o[0] = make_float4(r[0], r[1], r[2], r[3]);
    o[1] = make_float4(r[4], r[5], r[6], r[7]);
}

// ================= m97-structure GEMMs: 128x128 tile, BK=64, 4 waves, =================
// ================= single-buffered 32 KB LDS, global_load_lds w16, 2 syncs/iter ======

// ---------------- GEMM1: inter = relu(gather(xb) @ W1_e^T); fused W2->bf16 -----------
__global__ __launch_bounds__(256, 4) void gemm1_k(
    const unsigned short* __restrict__ xb,
    const unsigned short* __restrict__ w1b,
    const int* __restrict__ tok_list,
    unsigned short* __restrict__ inter,
    const float* __restrict__ w2f, unsigned short* __restrict__ w2b,
    int eb)
{
    constexpr int K = HID, T = K / 64;
    __shared__ __align__(16) unsigned short smem[16384];   // 32 KB
    unsigned short* As = smem;
    unsigned short* Bs = smem + 8192;

    // fused W2 conversion: 4096-block grid x 256 thr; 2 chunks/thread. Hides
    // under the compute-bound K-loop (gemm1 uses ~1.3 of 6.3 TB/s HBM).
    // Complete before gemm2 launches (same-stream ordering).
    if (w2f) {
        size_t g0 = (size_t)blockIdx.x * 256 + threadIdx.x;
#pragma unroll
        for (int q = 0; q < 2; ++q) {
            size_t g = g0 + (size_t)q * (4096 * 256);
            ((uint4*)w2b)[g] = packchunk(w2f, g);
        }
    }

    const int nblk = gridDim.x;
    const int lin  = blockIdx.x;
    const int wg   = (lin & 7) * (nblk >> 3) + (lin >> 3);  // XCD-bijective
    const int tn = wg & 15;           // NI/128
    const int tm = (wg >> 4) & 31;    // CAP/128
    const int ez = wg >> 9;
    const int e  = eb + ez;

    const int tid = threadIdx.x, lane = tid & 63, wave = tid >> 6;
    const int wr = wave >> 1, wc = wave & 1;
    const int gsl8 = ((lane & 7) ^ ((lane >> 3) & 7)) * 8;
    const int abase = (wr * 64 + (lane & 15)) * 64;
    const int bbase = (wc * 64 + (lane & 15)) * 64;
    const int phs[2] = { (((lane >> 4)) ^ (lane & 7)) * 8,
                         ((4 + (lane >> 4)) ^ (lane & 7)) * 8 };

    const int* tl = tok_list + e * CAP + tm * 128;
    const unsigned short* srcA[4];
    const unsigned short* srcB[4];
#pragma unroll
    for (int c = 0; c < 4; ++c) {
        int row = c * 32 + wave * 8 + (lane >> 3);
        srcA[c] = xb + (size_t)tl[row] * K + gsl8;
        srcB[c] = w1b + ((size_t)e * NI + tn * 128 + row) * K + gsl8;
    }

    f32x4 acc[4][4];
#pragma unroll
    for (int i = 0; i < 4; ++i)
#pragma unroll
        for (int j = 0; j < 4; ++j) acc[i][j] = (f32x4)0.f;

    for (int t = 0; t < T; ++t) {
#pragma unroll
        for (int c = 0; c < 4; ++c) {
            unsigned short* d = smem + (c * 32 + wave * 8) * 64;
            gload16(srcA[c] + t * 64, d);
            gload16(srcB[c] + t * 64, d + 8192);
        }
        __syncthreads();
#pragma unroll
        for (int ks = 0; ks < 2; ++ks) {
            s16x8 af[4], bf[4];
#pragma unroll
            for (int mi = 0; mi < 4; ++mi)
                af[mi] = *(const s16x8*)(As + abase + mi * 1024 + phs[ks]);
#pragma unroll
            for (int ni = 0; ni < 4; ++ni)
                bf[ni] = *(const s16x8*)(Bs + bbase + ni * 1024 + phs[ks]);
#pragma unroll
            for (int mi = 0; mi < 4; ++mi)
#pragma unroll
                for (int ni = 0; ni < 4; ++ni)
                    acc[mi][ni] = __builtin_amdgcn_mfma_f32_16x16x32_bf16(
                        af[mi], bf[ni], acc[mi][ni], 0, 0, 0);
        }
        __syncthreads();
    }

    // epilogue: relu -> swizzled LDS repack -> coalesced 16B stores
#pragma unroll
    for (int mi = 0; mi < 4; ++mi)
#pragma unroll
        for (int ni = 0; ni < 4; ++ni)
#pragma unroll
            for (int r = 0; r < 4; ++r) {
                int row = wr * 64 + mi * 16 + (lane >> 4) * 4 + r;
                int c   = wc * 64 + ni * 16 + (lane & 15);
                float v = acc[mi][ni][r];
                v = v > 0.f ? v : 0.f;
                smem[row * 128 + (((c >> 3) ^ (row & 7)) << 3) + (c & 7)] = f2bf(v);
            }
    __syncthreads();
    unsigned short* Cp = inter + ((size_t)ez * CAP + tm * 128) * NI + tn * 128;
#pragma unroll
    for (int it = 0; it < 8; ++it) {
        int v = tid + it * 256;
        int row = v >> 4, s = v & 15;
        uint4 val = *(const uint4*)&smem[row * 128 + ((s ^ (row & 7)) << 3)];
        *(uint4*)&Cp[(size_t)row * NI + s * 8] = val;
    }
}

// ---------------- GEMM2: out_e[slot] = inter @ W2_e^T  (or atomic fallback) ----------
__global__ __launch_bounds__(256, 4) void gemm2_k(
    const unsigned short* __restrict__ inter,
    const unsigned short* __restrict__ w2b,
    const int* __restrict__ tok_list,
    const float* __restrict__ w_list,
    float* __restrict__ out,
    unsigned short* __restrict__ out_e,   // non-null => combine mode
    int eb)
{
    constexpr int K = NI, T = K / 64;
    __shared__ __align__(16) unsigned short smem[16384];
    unsigned short* As = smem;
    unsigned short* Bs = smem + 8192;

    const int nblk = gridDim.x;
    const int lin  = blockIdx.x;
    const int wg   = (lin & 7) * (nblk >> 3) + (lin >> 3);
    const int tn = wg & 7;            // HID/128
    const int tm = (wg >> 3) & 31;    // CAP/128
    const int ez = wg >> 8;
    const int e  = eb + ez;

    const int tid = threadIdx.x, lane = tid & 63, wave = tid >> 6;
    const int wr = wave >> 1, wc = wave & 1;
    const int gsl8 = ((lane & 7) ^ ((lane >> 3) & 7)) * 8;
    const int abase = (wr * 64 + (lane & 15)) * 64;
    const int bbase = (wc * 64 + (lane & 15)) * 64;
    const int phs[2] = { (((lane >> 4)) ^ (lane & 7)) * 8,
                         ((4 + (lane >> 4)) ^ (lane & 7)) * 8 };

    const unsigned short* srcA[4];
    const unsigned short* srcB[4];
#pragma unroll
    for (int c = 0; c < 4; ++c) {
        int row = c * 32 + wave * 8 + (lane >> 3);
        srcA[c] = inter + ((size_t)ez * CAP + tm * 128 + row) * (size_t)K + gsl8;
        srcB[c] = w2b + ((size_t)e * HID + tn * 128 + row) * (size_t)K + gsl8;
    }

    f32x4 acc[4][4];
#pragma unroll
    for (int i = 0; i < 4; ++i)
#pragma unroll
        for (int j = 0; j < 4; ++j) acc[i][j] = (f32x4)0.f;

    for (int t = 0; t < T; ++t) {
#pragma unroll
        for (int c = 0; c < 4; ++c) {
            unsigned short* d = smem + (c * 32 + wave * 8) * 64;
            gload16(srcA[c] + t * 64, d);
            gload16(srcB[c] + t * 64, d + 8192);
        }
        __syncthreads();
#pragma unroll
        for (int ks = 0; ks < 2; ++ks) {
            s16x8 af[4], bf[4];
#pragma unroll
            for (int mi = 0; mi < 4; ++mi)
                af[mi] = *(const s16x8*)(As + abase + mi * 1024 + phs[ks]);
#pragma unroll
            for (int ni = 0; ni < 4; ++ni)
                bf[ni] = *(const s16x8*)(Bs + bbase + ni * 1024 + phs[ks]);
#pragma unroll
            for (int mi = 0; mi < 4; ++mi)
#pragma unroll
                for (int ni = 0; ni < 4; ++ni)
                    acc[mi][ni] = __builtin_amdgcn_mfma_f32_16x16x32_bf16(
                        af[mi], bf[ni], acc[mi][ni], 0, 0, 0);
        }
        __syncthreads();
    }

    if (out_e) {
        // combine mode: unweighted bf16 stores via swizzled LDS repack
#pragma unroll
        for (int mi = 0; mi < 4; ++mi)
#pragma unroll
            for (int ni = 0; ni < 4; ++ni)
#pragma unroll
                for (int r = 0; r < 4; ++r) {
                    int row = wr * 64 + mi * 16 + (lane >> 4) * 4 + r;
                    int c   = wc * 64 + ni * 16 + (lane & 15);
                    smem[row * 128 + (((c >> 3) ^ (row & 7)) << 3) + (c & 7)] = f2bf(acc[mi][ni][r]);
                }
        __syncthreads();
        unsigned short* Cp = out_e + ((size_t)e * CAP + tm * 128) * HID + tn * 128;
#pragma unroll
        for (int it = 0; it < 8; ++it) {
            int v = tid + it * 256;
            int row = v >> 4, s = v & 15;
            uint4 val = *(const uint4*)&smem[row * 128 + ((s ^ (row & 7)) << 3)];
            *(uint4*)&Cp[(size_t)row * HID + s * 8] = val;
        }
    } else {
        const int* tl   = tok_list + e * CAP + tm * 128;
        const float* wl = w_list  + e * CAP + tm * 128;
#pragma unroll
        for (int mi = 0; mi < 4; ++mi)
#pragma unroll
            for (int r = 0; r < 4; ++r) {
                int rrow = wr * 64 + mi * 16 + (lane >> 4) * 4 + r;
                int tok  = tl[rrow];
                float w  = wl[rrow];
                float* orow = out + (size_t)tok * HID + tn * 128 + wc * 64;
#pragma unroll
                for (int ni = 0; ni < 4; ++ni)
                    atomicAdd(&orow[ni * 16 + (lane & 15)], acc[mi][ni][r] * w);
            }
    }
}

extern "C" void kernel_launch(void* const* d_in, const int* in_sizes, int n_in,
                              void* d_out, int out_size, void* d_ws, size_t ws_size,
                              hipStream_t stream)
{
    const float* x   = (const float*)d_in[0];
    const float* emb = (const float*)d_in[1];
    const float* W1  = (const float*)d_in[2];
    const float* W2  = (const float*)d_in[3];
    float* out = (float*)d_out;

    size_t off = 0;
    auto alloc = [&](size_t bytes) -> void* {
        void* p = (char*)d_ws + off;
        off += (bytes + 255) & ~(size_t)255;
        return p;
    };
    const size_t sz_w  = (size_t)NE * NI * HID * 2;
    const size_t sz_xb = (size_t)N_TOK * HID * 2;

    int*   tok_list = (int*)alloc((size_t)NE * CAP * 4);
    float* w_list   = (float*)alloc((size_t)NE * CAP * 4);
    int2*  smap     = (int2*)alloc((size_t)N_TOK * 8);
    unsigned short* w1b = (unsigned short*)alloc(sz_w);
    unsigned short* w2b = (unsigned short*)alloc(sz_w);
    unsigned short* xb  = (unsigned short*)alloc(sz_xb);

    unsigned short* inter = (unsigned short*)((char*)d_ws + off);
    size_t avail = ws_size > off ? ws_size - off : 0;
    const size_t per_e = (size_t)CAP * NI * 2;
    int G = (avail >= 8 * per_e) ? 8 : (avail >= 4 * per_e) ? 4
          : (avail >= 2 * per_e) ? 2 : 1;
    const bool combine = (G == 8);
    unsigned short* out_e = combine ? xb : nullptr;   // aliases xb (dead after gemm1)

    int2*   r_e = (int2*)inter;
    float2* r_w = (float2*)((char*)inter + (size_t)N_TOK * 8);
    int*    bc  = (int*)((char*)inter + (size_t)N_TOK * 16);
    int*    bb  = bc + (N_TOK / 1024) * NE;

    if (!combine)
        hipMemsetAsync(d_out, 0, (size_t)N_TOK * HID * 4, stream);
    hipMemsetAsync(tok_list, 0, (size_t)NE * CAP * 4, stream);
    hipMemsetAsync(w_list, 0, (size_t)NE * CAP * 4, stream);

    if (!combine) {
        // fallback: standalone weight conversion (grid shapes differ from the
        // fused-conversion assumptions)
        cvt2_kernel<<<2048, 256, 0, stream>>>(W1, w1b, (size_t)NE * NI * HID / 8,
                                              W2, w2b, (size_t)NE * HID * NI / 8);
    }

    // combine mode: router converts W1 (1 chunk/thread, exact grid match);
    // gemm1 converts W2 (hidden under compute)
    router_kernel<<<N_TOK / 4, 256, 0, stream>>>(x, emb, r_e, r_w, xb,
                                                 combine ? W1 : nullptr, w1b);
    count_kernel<<<N_TOK / 1024, 1024, 0, stream>>>(r_e, bc);
    prefix_kernel<<<1, 64, 0, stream>>>(bc, bb);
    assign_kernel<<<N_TOK / 1024, 1024, 0, stream>>>(r_e, r_w, bb, tok_list, w_list, smap);

    for (int eb = 0; eb < NE; eb += G) {
        gemm1_k<<<dim3(16 * 32 * G), 256, 0, stream>>>(
            xb, w1b, tok_list, inter,
            (combine && eb == 0) ? W2 : nullptr, w2b, eb);
        gemm2_k<<<dim3(8 * 32 * G), 256, 0, stream>>>(
            inter, w2b, tok_list, w_list, out, out_e, eb);
    }
    if (combine)
        combine_kernel<<<N_TOK / 2, 256, 0, stream>>>(out_e, smap, w_list, out);
}